// Round 1
// baseline (132.909 us; speedup 1.0000x reference)
//
#include <hip/hip_runtime.h>

// Conv2d int32 (values fit int8) via implicit GEMM, v8: deep-pipelined conv_main.
// x8: [chunk8][b16][row58][slot58][32B] (halo zeroed, granule parity swizzle (g+slot)&1)
// w8: [cotile4][chunk8][co64][tap9][32B] (granule parity swizzle (g+co)&1)
// v8 = v7 with conv_main's 2-buffer __syncthreads pipeline replaced by a
// 3-buffer, 2-chunk-deep prefetch using counted s_waitcnt vmcnt(6) + raw
// s_barrier (T3/T4 from the CDNA4 guide). Staging is restructured so every
// thread issues exactly 6 x 16B global_load_lds per chunk (3072 granules /
// 512 threads, wave-uniform split at the 1152-granule w/x boundary), making
// the counted vmcnt wave-uniform and exact. pack_all unchanged from v7.

typedef int v4i  __attribute__((ext_vector_type(4)));
typedef int v16i __attribute__((ext_vector_type(16)));

#define X8_ROWSTRIDE 1856                 // 58 slots * 32 B
#define X8_IMGSTRIDE 107648               // 58 rows * 1856
#define X8_BYTES     13778944             // 128 images (8 chunks x 16 b)
#define W8_CHUNK     18432                // 64 co * 9 tap * 32 B
#define XS_OFF       55296                // after 3 w-buffers
#define XS_BUF       30720                // 16 rows = 29,696 staged, rounded up

typedef const __attribute__((address_space(1))) unsigned char* gptr_t;
typedef __attribute__((address_space(3))) unsigned char* lptr_t;

__device__ __forceinline__ int pack4(const int* p, int stride) {
  return (p[0] & 255) | ((p[stride] & 255) << 8) |
         ((p[2 * stride] & 255) << 16) | ((p[3 * stride] & 255) << 24);
}

// ---- fused prepass (identical to v7) ----
// blocks [0,784): x interior. 200,704 threads: (cb128, row 1..56, sq 0..13, srcg 0..1)
//   each loads 16 dwordx4 (16 ch x 4 consecutive iw) and stores 4 granules.
// blocks [784,1012): halo zero stores (58,368 granules = 228 blocks exact).
// blocks [1012,1156): w pack (36,864 granules = 144 blocks exact).
__global__ __launch_bounds__(256)
void pack_all(const int* __restrict__ x, const int* __restrict__ wgt,
              unsigned char* __restrict__ ws8) {
  const int blk = blockIdx.x;
  if (blk < 784) {
    const int gid = blk * 256 + threadIdx.x;
    const int srcg = gid & 1;
    int t = gid >> 1;
    const int sq = t % 14;  t /= 14;      // slots 4sq+1 .. 4sq+4, iw 4sq .. 4sq+3
    const int row = t % 56 + 1;           // 1..56
    const int cb  = t / 56;               // chunk*16 + b
    const int chunk = cb >> 4, b = cb & 15;
    const int ci0 = chunk * 32 + srcg * 16;
    const int* src = x + (b * 256 + ci0) * 3136 + (row - 1) * 56 + 4 * sq;
    v4i L[16];
    #pragma unroll
    for (int ch = 0; ch < 16; ++ch) L[ch] = *(const v4i*)(src + ch * 3136);
    unsigned char* dstrow = ws8 + cb * X8_IMGSTRIDE + row * X8_ROWSTRIDE;
    #pragma unroll
    for (int j = 0; j < 4; ++j) {
      const int slot = 4 * sq + 1 + j;
      v4i g;
      #pragma unroll
      for (int d = 0; d < 4; ++d)
        g[d] = (L[4 * d][j] & 255) | ((L[4 * d + 1][j] & 255) << 8) |
               ((L[4 * d + 2][j] & 255) << 16) | ((L[4 * d + 3][j] & 255) << 24);
      const int p = (srcg + slot) & 1;    // inverse of srcg=(p+slot)&1
      *(v4i*)(dstrow + slot * 32 + p * 16) = g;
    }
  } else if (blk < 1012) {
    const int g2 = (blk - 784) * 256 + threadIdx.x;   // 58,368 granules
    const int cb = g2 / 456;
    const int r  = g2 - cb * 456;
    int off;
    if (r < 232) {                       // rows 0 and 57, all 58 slots x 2 granules
      const int row = r < 116 ? 0 : 57;
      const int rr = r % 116;
      off = row * X8_ROWSTRIDE + (rr >> 1) * 32 + (rr & 1) * 16;
    } else {                             // rows 1..56, slots 0 and 57
      const int r2 = r - 232;            // 0..223
      const int row = (r2 >> 2) + 1;
      const int slot = (r2 & 2) ? 57 : 0;
      off = row * X8_ROWSTRIDE + slot * 32 + (r2 & 1) * 16;
    }
    *(v4i*)(ws8 + cb * X8_IMGSTRIDE + off) = (v4i){0, 0, 0, 0};
  } else {
    const int gw = (blk - 1012) * 256 + threadIdx.x;  // 36,864 granules exact
    const int p = gw & 1;
    int t = gw >> 1;
    const int tap = t % 9;  t /= 9;
    const int co = t & 63;
    const int tcc = t >> 6;              // 0..287: chunk 0..7, cotile 0..3
    const int chunk = tcc & 7, cotile = tcc >> 3;
    const int srcg = (p + co) & 1;
    const int ci0 = chunk * 32 + srcg * 16;
    const int* src = wgt + ((cotile * 64 + co) * 256 + ci0) * 9 + tap;
    v4i v = (v4i){pack4(src, 9), pack4(src + 36, 9),
                  pack4(src + 72, 9), pack4(src + 108, 9)};
    *(v4i*)(ws8 + X8_BYTES + (t * 9 + tap) * 32 + p * 16) = v;
  }
}

// ---- stage one chunk (w 18,432 B + x 30,720 B = 3072 granules) into buffer buf ----
// Exactly 6 x 16B global_load_lds per thread (512 threads): granule
// g_i = tid + i*512, i=0..5; g < 1152 -> w, else x (split at i=2 is
// wave-uniform: tid<128 = waves 0-1). Counted vmcnt relies on this.
__device__ __forceinline__ void stage_chunk(const unsigned char* wg,
                                            const unsigned char* xg,
                                            unsigned char* ldsb, int c, int buf,
                                            int tid) {
  const unsigned char* wsrc = wg + c * W8_CHUNK;
  const unsigned char* xsrc = xg + c * (16 * X8_IMGSTRIDE);
  unsigned char* wdst = ldsb + buf * W8_CHUNK;
  unsigned char* xdst = ldsb + XS_OFF + buf * XS_BUF;
  #pragma unroll
  for (int i = 0; i < 2; ++i) {          // g in [0,1024): w
    const int o = (tid + i * 512) * 16;
    __builtin_amdgcn_global_load_lds((gptr_t)(wsrc + o), (lptr_t)(wdst + o), 16, 0, 0);
  }
  if (tid < 128) {                       // g in [1024,1152): w (waves 0-1)
    const int o = (1024 + tid) * 16;
    __builtin_amdgcn_global_load_lds((gptr_t)(wsrc + o), (lptr_t)(wdst + o), 16, 0, 0);
  } else {                               // x granules [0,384) (waves 2-7)
    const int o = (tid - 128) * 16;
    __builtin_amdgcn_global_load_lds((gptr_t)(xsrc + o), (lptr_t)(xdst + o), 16, 0, 0);
  }
  #pragma unroll
  for (int i = 0; i < 3; ++i) {          // x granules [384,1920)
    const int o = (384 + tid + i * 512) * 16;
    __builtin_amdgcn_global_load_lds((gptr_t)(xsrc + o), (lptr_t)(xdst + o), 16, 0, 0);
  }
}

// ---- main kernel: 3-buffer, 2-deep prefetch, counted vmcnt ----
__global__ __launch_bounds__(512, 2)
void conv_main(const unsigned char* __restrict__ ws8, const int* __restrict__ bias,
               int* __restrict__ out) {
  __shared__ __align__(16) unsigned char lds[3 * W8_CHUNK + 3 * XS_BUF];  // 147,456 B
  __shared__ int bls[64];

  const int tid = threadIdx.x, lane = tid & 63, wv = tid >> 6;  // wv 0..7
  const int n = lane & 31, gq = lane >> 5;
  const int tc = blockIdx.y;             // co tile of 64
  const int hb = blockIdx.x;             // hg*16 + b
  const int hg = hb >> 4, b = hb & 15;
  const int h0 = hg * 14;

  if (tid < 64) {
    bls[tid] = bias[tc * 64 + tid];
    // drain the ds_write before this wave reaches the first raw s_barrier
    asm volatile("s_waitcnt lgkmcnt(0)" ::: "memory");
  }

  const int abase = n * 288 + (((gq + n) & 1) << 4);
  int boff[3][4];
  #pragma unroll
  for (int kw = 0; kw < 3; ++kw)
    #pragma unroll
    for (int bt = 0; bt < 4; ++bt) {
      int slot = bt * 16 + (n & 15) + kw;
      if (slot > 57) slot = 57;
      boff[kw][bt] = slot * 32 + (((gq + slot) & 1) << 4);
    }
  const int rbase = (2 * wv + (n >> 4)) * X8_ROWSTRIDE;   // valid for wv<7

  v16i acc[2][4];
  #pragma unroll
  for (int i = 0; i < 2; ++i)
    #pragma unroll
    for (int j = 0; j < 4; ++j)
      acc[i][j] = (v16i){0,0,0,0,0,0,0,0,0,0,0,0,0,0,0,0};

  const unsigned char* wg = ws8 + X8_BYTES + tc * (8 * W8_CHUNK);
  const unsigned char* xg = ws8 + b * X8_IMGSTRIDE + h0 * X8_ROWSTRIDE;

  stage_chunk(wg, xg, lds, 0, 0, tid);   // 6 loads in flight
  stage_chunk(wg, xg, lds, 1, 1, tid);   // 12 loads in flight
  int buf = 0, nbuf = 2;
  for (int c = 0; c < 8; ++c) {
    // wait for stage(c); keep stage(c+1)'s 6 loads in flight
    if (c < 7) asm volatile("s_waitcnt vmcnt(6)" ::: "memory");
    else       asm volatile("s_waitcnt vmcnt(0)" ::: "memory");
    __builtin_amdgcn_s_barrier();
    asm volatile("" ::: "memory");
    // buffer nbuf = (c+2)%3 was last read by compute(c-1), which every wave
    // finished before this barrier -> safe to overwrite now.
    if (c < 6) stage_chunk(wg, xg, lds, c + 2, nbuf, tid);
    if (wv < 7) {
      const unsigned char* wls = lds + buf * W8_CHUNK;
      const unsigned char* xs  = lds + XS_OFF + buf * XS_BUF;
      #pragma unroll
      for (int kh = 0; kh < 3; ++kh) {
        const unsigned char* xr = xs + rbase + kh * X8_ROWSTRIDE;
        #pragma unroll
        for (int kw = 0; kw < 3; ++kw) {
          const int tap = kh * 3 + kw;
          const v4i a0 = *(const v4i*)(wls + abase + tap * 32);
          const v4i a1 = *(const v4i*)(wls + 9216 + abase + tap * 32);
          #pragma unroll
          for (int bt = 0; bt < 4; ++bt) {
            const v4i bb = *(const v4i*)(xr + boff[kw][bt]);
            acc[0][bt] = __builtin_amdgcn_mfma_i32_32x32x32_i8(a0, bb, acc[0][bt], 0, 0, 0);
            acc[1][bt] = __builtin_amdgcn_mfma_i32_32x32x32_i8(a1, bb, acc[1][bt], 0, 0, 0);
          }
        }
      }
    }
    buf  = (buf  == 2) ? 0 : buf  + 1;
    nbuf = (nbuf == 2) ? 0 : nbuf + 1;
  }

  if (wv >= 7) return;
  const int h = h0 + 2 * wv + (n >> 4);   // <= 55 always
  const int wbase = lane & 15;
  #pragma unroll
  for (int ct = 0; ct < 2; ++ct) {
    #pragma unroll
    for (int r = 0; r < 16; ++r) {
      const int co64 = ct * 32 + (r & 3) + 8 * (r >> 2) + 4 * gq;
      const int bv = bls[co64];
      int* orow = out + ((b * 256 + tc * 64 + co64) * 56 + h) * 56;
      #pragma unroll
      for (int bt = 0; bt < 4; ++bt) {
        const int w0 = bt * 16 + wbase;
        if (w0 < 56) orow[w0] = acc[ct][bt][r] + bv;
      }
    }
  }
}

extern "C" void kernel_launch(void* const* d_in, const int* in_sizes, int n_in,
                              void* d_out, int out_size, void* d_ws, size_t ws_size,
                              hipStream_t stream) {
  const int* x    = (const int*)d_in[0];
  const int* w    = (const int*)d_in[1];
  const int* bias = (const int*)d_in[2];
  unsigned char* ws8 = (unsigned char*)d_ws;   // x8 then w8 (~14.4 MB)
  hipLaunchKernelGGL(pack_all, dim3(1156), dim3(256), 0, stream, x, w, ws8);
  hipLaunchKernelGGL(conv_main, dim3(64, 4, 1), dim3(512), 0, stream,
                     ws8, bias, (int*)d_out);
}

// Round 2
// 132.131 us; speedup vs baseline: 1.0059x; 1.0059x over previous
//
#include <hip/hip_runtime.h>

// Conv2d int32 (values fit int8) via implicit GEMM, v9: bank-conflict-free swizzle.
// x8: [chunk8][b16][row58][slot58][32B] (halo zeroed, granule parity (g+(slot>>2))&1)
// w8: [cotile4][chunk8][co64][tap9][32B] (granule parity (g+(co>>2))&1)
// v9 = v8 with the granule-parity swizzle upgraded from (g+slot)&1 / (g+co)&1 to
// (g+(slot>>2))&1 / (g+(co>>2))&1. Old parity was constant within each
// slot%4 class -> a 16-lane phase of ds_read_b128 hit only 4 of 8 mod-128
// positions, 4 lanes each = 4-deep bank serialization (measured +4.2 cyc/read,
// SQ_LDS_BANK_CONFLICT 3.27M). New parity alternates with slot>>2 -> 8
// positions x 2 lanes = conflict-free. Pure layout permutation: pack_all
// write side + conv read side changed together; linear staging untouched.

typedef int v4i  __attribute__((ext_vector_type(4)));
typedef int v16i __attribute__((ext_vector_type(16)));

#define X8_ROWSTRIDE 1856                 // 58 slots * 32 B
#define X8_IMGSTRIDE 107648               // 58 rows * 1856
#define X8_BYTES     13778944             // 128 images (8 chunks x 16 b)
#define W8_CHUNK     18432                // 64 co * 9 tap * 32 B
#define XS_OFF       55296                // after 3 w-buffers
#define XS_BUF       30720                // 16 rows = 29,696 staged, rounded up

typedef const __attribute__((address_space(1))) unsigned char* gptr_t;
typedef __attribute__((address_space(3))) unsigned char* lptr_t;

__device__ __forceinline__ int pack4(const int* p, int stride) {
  return (p[0] & 255) | ((p[stride] & 255) << 8) |
         ((p[2 * stride] & 255) << 16) | ((p[3 * stride] & 255) << 24);
}

// ---- fused prepass ----
// blocks [0,784): x interior. 200,704 threads: (cb128, row 1..56, sq 0..13, srcg 0..1)
//   each loads 16 dwordx4 (16 ch x 4 consecutive iw) and stores 4 granules.
// blocks [784,1012): halo zero stores (58,368 granules = 228 blocks exact).
// blocks [1012,1156): w pack (36,864 granules = 144 blocks exact).
__global__ __launch_bounds__(256)
void pack_all(const int* __restrict__ x, const int* __restrict__ wgt,
              unsigned char* __restrict__ ws8) {
  const int blk = blockIdx.x;
  if (blk < 784) {
    const int gid = blk * 256 + threadIdx.x;
    const int srcg = gid & 1;
    int t = gid >> 1;
    const int sq = t % 14;  t /= 14;      // slots 4sq+1 .. 4sq+4, iw 4sq .. 4sq+3
    const int row = t % 56 + 1;           // 1..56
    const int cb  = t / 56;               // chunk*16 + b
    const int chunk = cb >> 4, b = cb & 15;
    const int ci0 = chunk * 32 + srcg * 16;
    const int* src = x + (b * 256 + ci0) * 3136 + (row - 1) * 56 + 4 * sq;
    v4i L[16];
    #pragma unroll
    for (int ch = 0; ch < 16; ++ch) L[ch] = *(const v4i*)(src + ch * 3136);
    unsigned char* dstrow = ws8 + cb * X8_IMGSTRIDE + row * X8_ROWSTRIDE;
    #pragma unroll
    for (int j = 0; j < 4; ++j) {
      const int slot = 4 * sq + 1 + j;
      v4i g;
      #pragma unroll
      for (int d = 0; d < 4; ++d)
        g[d] = (L[4 * d][j] & 255) | ((L[4 * d + 1][j] & 255) << 8) |
               ((L[4 * d + 2][j] & 255) << 16) | ((L[4 * d + 3][j] & 255) << 24);
      const int p = (srcg + (slot >> 2)) & 1;   // inverse of srcg=(p+(slot>>2))&1
      *(v4i*)(dstrow + slot * 32 + p * 16) = g;
    }
  } else if (blk < 1012) {
    const int g2 = (blk - 784) * 256 + threadIdx.x;   // 58,368 granules
    const int cb = g2 / 456;
    const int r  = g2 - cb * 456;
    int off;
    if (r < 232) {                       // rows 0 and 57, all 58 slots x 2 granules
      const int row = r < 116 ? 0 : 57;
      const int rr = r % 116;
      off = row * X8_ROWSTRIDE + (rr >> 1) * 32 + (rr & 1) * 16;
    } else {                             // rows 1..56, slots 0 and 57
      const int r2 = r - 232;            // 0..223
      const int row = (r2 >> 2) + 1;
      const int slot = (r2 & 2) ? 57 : 0;
      off = row * X8_ROWSTRIDE + slot * 32 + (r2 & 1) * 16;
    }
    *(v4i*)(ws8 + cb * X8_IMGSTRIDE + off) = (v4i){0, 0, 0, 0};
  } else {
    const int gw = (blk - 1012) * 256 + threadIdx.x;  // 36,864 granules exact
    const int p = gw & 1;
    int t = gw >> 1;
    const int tap = t % 9;  t /= 9;
    const int co = t & 63;
    const int tcc = t >> 6;              // 0..287: chunk 0..7, cotile 0..3
    const int chunk = tcc & 7, cotile = tcc >> 3;
    const int srcg = (p + (co >> 2)) & 1;   // inverse of p=(srcg+(co>>2))&1
    const int ci0 = chunk * 32 + srcg * 16;
    const int* src = wgt + ((cotile * 64 + co) * 256 + ci0) * 9 + tap;
    v4i v = (v4i){pack4(src, 9), pack4(src + 36, 9),
                  pack4(src + 72, 9), pack4(src + 108, 9)};
    *(v4i*)(ws8 + X8_BYTES + (t * 9 + tap) * 32 + p * 16) = v;
  }
}

// ---- stage one chunk (w 18,432 B + x 30,720 B = 3072 granules) into buffer buf ----
// Exactly 6 x 16B global_load_lds per thread (512 threads): granule
// g_i = tid + i*512, i=0..5; g < 1152 -> w, else x (split at i=2 is
// wave-uniform: tid<128 = waves 0-1). Counted vmcnt relies on this.
__device__ __forceinline__ void stage_chunk(const unsigned char* wg,
                                            const unsigned char* xg,
                                            unsigned char* ldsb, int c, int buf,
                                            int tid) {
  const unsigned char* wsrc = wg + c * W8_CHUNK;
  const unsigned char* xsrc = xg + c * (16 * X8_IMGSTRIDE);
  unsigned char* wdst = ldsb + buf * W8_CHUNK;
  unsigned char* xdst = ldsb + XS_OFF + buf * XS_BUF;
  #pragma unroll
  for (int i = 0; i < 2; ++i) {          // g in [0,1024): w
    const int o = (tid + i * 512) * 16;
    __builtin_amdgcn_global_load_lds((gptr_t)(wsrc + o), (lptr_t)(wdst + o), 16, 0, 0);
  }
  if (tid < 128) {                       // g in [1024,1152): w (waves 0-1)
    const int o = (1024 + tid) * 16;
    __builtin_amdgcn_global_load_lds((gptr_t)(wsrc + o), (lptr_t)(wdst + o), 16, 0, 0);
  } else {                               // x granules [0,384) (waves 2-7)
    const int o = (tid - 128) * 16;
    __builtin_amdgcn_global_load_lds((gptr_t)(xsrc + o), (lptr_t)(xdst + o), 16, 0, 0);
  }
  #pragma unroll
  for (int i = 0; i < 3; ++i) {          // x granules [384,1920)
    const int o = (384 + tid + i * 512) * 16;
    __builtin_amdgcn_global_load_lds((gptr_t)(xsrc + o), (lptr_t)(xdst + o), 16, 0, 0);
  }
}

// ---- main kernel: 3-buffer, 2-deep prefetch, counted vmcnt ----
__global__ __launch_bounds__(512, 2)
void conv_main(const unsigned char* __restrict__ ws8, const int* __restrict__ bias,
               int* __restrict__ out) {
  __shared__ __align__(16) unsigned char lds[3 * W8_CHUNK + 3 * XS_BUF];  // 147,456 B
  __shared__ int bls[64];

  const int tid = threadIdx.x, lane = tid & 63, wv = tid >> 6;  // wv 0..7
  const int n = lane & 31, gq = lane >> 5;
  const int tc = blockIdx.y;             // co tile of 64
  const int hb = blockIdx.x;             // hg*16 + b
  const int hg = hb >> 4, b = hb & 15;
  const int h0 = hg * 14;

  if (tid < 64) {
    bls[tid] = bias[tc * 64 + tid];
    // drain the ds_write before this wave reaches the first raw s_barrier
    asm volatile("s_waitcnt lgkmcnt(0)" ::: "memory");
  }

  const int abase = n * 288 + (((gq + (n >> 2)) & 1) << 4);
  int boff[3][4];
  #pragma unroll
  for (int kw = 0; kw < 3; ++kw)
    #pragma unroll
    for (int bt = 0; bt < 4; ++bt) {
      int slot = bt * 16 + (n & 15) + kw;
      if (slot > 57) slot = 57;
      boff[kw][bt] = slot * 32 + (((gq + (slot >> 2)) & 1) << 4);
    }
  const int rbase = (2 * wv + (n >> 4)) * X8_ROWSTRIDE;   // valid for wv<7

  v16i acc[2][4];
  #pragma unroll
  for (int i = 0; i < 2; ++i)
    #pragma unroll
    for (int j = 0; j < 4; ++j)
      acc[i][j] = (v16i){0,0,0,0,0,0,0,0,0,0,0,0,0,0,0,0};

  const unsigned char* wg = ws8 + X8_BYTES + tc * (8 * W8_CHUNK);
  const unsigned char* xg = ws8 + b * X8_IMGSTRIDE + h0 * X8_ROWSTRIDE;

  stage_chunk(wg, xg, lds, 0, 0, tid);   // 6 loads in flight
  stage_chunk(wg, xg, lds, 1, 1, tid);   // 12 loads in flight
  int buf = 0, nbuf = 2;
  for (int c = 0; c < 8; ++c) {
    // wait for stage(c); keep stage(c+1)'s 6 loads in flight
    if (c < 7) asm volatile("s_waitcnt vmcnt(6)" ::: "memory");
    else       asm volatile("s_waitcnt vmcnt(0)" ::: "memory");
    __builtin_amdgcn_s_barrier();
    asm volatile("" ::: "memory");
    // buffer nbuf = (c+2)%3 was last read by compute(c-1), which every wave
    // finished before this barrier -> safe to overwrite now.
    if (c < 6) stage_chunk(wg, xg, lds, c + 2, nbuf, tid);
    if (wv < 7) {
      const unsigned char* wls = lds + buf * W8_CHUNK;
      const unsigned char* xs  = lds + XS_OFF + buf * XS_BUF;
      #pragma unroll
      for (int kh = 0; kh < 3; ++kh) {
        const unsigned char* xr = xs + rbase + kh * X8_ROWSTRIDE;
        #pragma unroll
        for (int kw = 0; kw < 3; ++kw) {
          const int tap = kh * 3 + kw;
          const v4i a0 = *(const v4i*)(wls + abase + tap * 32);
          const v4i a1 = *(const v4i*)(wls + 9216 + abase + tap * 32);
          #pragma unroll
          for (int bt = 0; bt < 4; ++bt) {
            const v4i bb = *(const v4i*)(xr + boff[kw][bt]);
            acc[0][bt] = __builtin_amdgcn_mfma_i32_32x32x32_i8(a0, bb, acc[0][bt], 0, 0, 0);
            acc[1][bt] = __builtin_amdgcn_mfma_i32_32x32x32_i8(a1, bb, acc[1][bt], 0, 0, 0);
          }
        }
      }
    }
    buf  = (buf  == 2) ? 0 : buf  + 1;
    nbuf = (nbuf == 2) ? 0 : nbuf + 1;
  }

  if (wv >= 7) return;
  const int h = h0 + 2 * wv + (n >> 4);   // <= 55 always
  const int wbase = lane & 15;
  #pragma unroll
  for (int ct = 0; ct < 2; ++ct) {
    #pragma unroll
    for (int r = 0; r < 16; ++r) {
      const int co64 = ct * 32 + (r & 3) + 8 * (r >> 2) + 4 * gq;
      const int bv = bls[co64];
      int* orow = out + ((b * 256 + tc * 64 + co64) * 56 + h) * 56;
      #pragma unroll
      for (int bt = 0; bt < 4; ++bt) {
        const int w0 = bt * 16 + wbase;
        if (w0 < 56) orow[w0] = acc[ct][bt][r] + bv;
      }
    }
  }
}

extern "C" void kernel_launch(void* const* d_in, const int* in_sizes, int n_in,
                              void* d_out, int out_size, void* d_ws, size_t ws_size,
                              hipStream_t stream) {
  const int* x    = (const int*)d_in[0];
  const int* w    = (const int*)d_in[1];
  const int* bias = (const int*)d_in[2];
  unsigned char* ws8 = (unsigned char*)d_ws;   // x8 then w8 (~14.4 MB)
  hipLaunchKernelGGL(pack_all, dim3(1156), dim3(256), 0, stream, x, w, ws8);
  hipLaunchKernelGGL(conv_main, dim3(64, 4, 1), dim3(512), 0, stream,
                     ws8, bias, (int*)d_out);
}